// Round 7
// baseline (507.637 us; speedup 1.0000x reference)
//
#include <hip/hip_runtime.h>
#include <hip/hip_fp16.h>

#define NN 100000
#define NPAD 100096   // 64*1564
#define EE 3200000
#define HH 128
#define CC 40

typedef _Float16 f16x8 __attribute__((ext_vector_type(8)));
typedef float f32x4 __attribute__((ext_vector_type(4)));

// tanh(x) = (e^2x - 1)/(e^2x + 1); clamp avoids inf*0=NaN. ~6 VALU ops.
__device__ __forceinline__ float fast_tanh(float x) {
    float t = __expf(2.f * fminf(x, 15.f));
    return (t - 1.f) * __builtin_amdgcn_rcpf(t + 1.f);
}

// rp[i] = lower_bound(edge_dst, i) — edge_dst is sorted.
__global__ void build_rp(const int* __restrict__ dst, int* __restrict__ rp) {
    int i = blockIdx.x * blockDim.x + threadIdx.x;
    if (i > NN) return;
    int lo = 0, hi = EE;
    while (lo < hi) {
        int mid = (lo + hi) >> 1;
        if (dst[mid] < i) lo = mid + 1; else hi = mid;
    }
    rp[i] = lo;
}

// prep: x->fp16; edges packed to 4B (src 17b | w 15b fixed); weights fp16^T.
__global__ __launch_bounds__(256) void prep_all(const float* __restrict__ x,
                                                const int* __restrict__ src,
                                                const float* __restrict__ w,
                                                const float* __restrict__ W0,
                                                const float* __restrict__ W1,
                                                const float* __restrict__ W2,
                                                __half* __restrict__ xh,
                                                unsigned* __restrict__ ewp,
                                                __half* __restrict__ W0t,
                                                __half* __restrict__ W1t,
                                                __half* __restrict__ W2t) {
    int b = blockIdx.x, tid = threadIdx.x;
    if (b < 6250) {                       // x: 12.8M elems, 8/thread
        int base = (b * 256 + tid) * 8;
        float4 a = *(const float4*)(x + base);
        float4 c = *(const float4*)(x + base + 4);
        __half2 h[4];
        h[0] = __floats2half2_rn(a.x, a.y);
        h[1] = __floats2half2_rn(a.z, a.w);
        h[2] = __floats2half2_rn(c.x, c.y);
        h[3] = __floats2half2_rn(c.z, c.w);
        *(float4*)(xh + base) = *(float4*)h;
    } else if (b < 9375) {                // pack 4 edges/thread
        int i = (b - 6250) * 256 + tid;   // < 800000
        int4 s = ((const int4*)src)[i];
        float4 f = ((const float4*)w)[i];
        uint4 p;
        p.x = (unsigned)s.x | ((unsigned)(f.x * 32767.f + 0.5f) << 17);
        p.y = (unsigned)s.y | ((unsigned)(f.y * 32767.f + 0.5f) << 17);
        p.z = (unsigned)s.z | ((unsigned)(f.z * 32767.f + 0.5f) << 17);
        p.w = (unsigned)s.w | ((unsigned)(f.w * 32767.f + 0.5f) << 17);
        ((uint4*)ewp)[i] = p;
    } else {                              // W0t,W1t [128][128]; W2t [64][128]
        int i = (b - 9375) * 256 + tid;
        if (i < HH * HH) {
            int c = i >> 7, k = i & 127;
            W0t[i] = __float2half_rn(W0[k * HH + c]);
            W1t[i] = __float2half_rn(W1[k * HH + c]);
        }
        if (i < 64 * HH) {
            int c = i >> 7, k = i & 127;
            W2t[i] = __float2half_rn(c < CC ? W2[k * CC + c] : 0.f);
        }
    }
}

#define EDEC_W(v) ((float)((v) >> 17) * (1.f / 32767.f))
#define EDEC_S(v) ((v) & 131071u)

// spmm for a 16-node tile (wave-private). Lane l owns features 2l,2l+1.
// Edge metadata is wave-uniform (scalar-load eligible); gathers are per-lane.
__device__ __forceinline__ void spmm_tile(const __half2* __restrict__ h2,
                                          const unsigned* __restrict__ ewp,
                                          const int* __restrict__ rp,
                                          int n0, int l,
                                          _Float16 (* __restrict__ As)[136]) {
#pragma unroll 1
    for (int i = 0; i < 16; ++i) {
        int node = n0 + i;
        int ia = node <= NN ? node : NN;
        int ib = node + 1 <= NN ? node + 1 : NN;
        int e0 = __builtin_amdgcn_readfirstlane(rp[ia]);
        int e1 = __builtin_amdgcn_readfirstlane(rp[ib]);
        float accx = 0.f, accy = 0.f;
        int e = e0;
        while ((e & 3) && e < e1) {       // peel to 16B alignment of ewp+e
            unsigned v = ewp[e];
            float wk = EDEC_W(v);
            float2 f = __half22float2(h2[(size_t)EDEC_S(v) * 64 + l]);
            accx = fmaf(wk, f.x, accx); accy = fmaf(wk, f.y, accy);
            ++e;
        }
        int e8 = e + ((e1 - e) & ~7);
#pragma unroll 1
        for (; e < e8; e += 8) {          // 8 gathers in flight
            uint4 pa = *(const uint4*)(ewp + e);
            uint4 pb = *(const uint4*)(ewp + e + 4);
            __half2 r0 = h2[(size_t)EDEC_S(pa.x) * 64 + l];
            __half2 r1 = h2[(size_t)EDEC_S(pa.y) * 64 + l];
            __half2 r2 = h2[(size_t)EDEC_S(pa.z) * 64 + l];
            __half2 r3 = h2[(size_t)EDEC_S(pa.w) * 64 + l];
            __half2 r4 = h2[(size_t)EDEC_S(pb.x) * 64 + l];
            __half2 r5 = h2[(size_t)EDEC_S(pb.y) * 64 + l];
            __half2 r6 = h2[(size_t)EDEC_S(pb.z) * 64 + l];
            __half2 r7 = h2[(size_t)EDEC_S(pb.w) * 64 + l];
            float2 f0 = __half22float2(r0), f1 = __half22float2(r1);
            float2 f2 = __half22float2(r2), f3 = __half22float2(r3);
            float2 f4 = __half22float2(r4), f5 = __half22float2(r5);
            float2 f6 = __half22float2(r6), f7 = __half22float2(r7);
            float w0 = EDEC_W(pa.x), w1 = EDEC_W(pa.y), w2 = EDEC_W(pa.z), w3 = EDEC_W(pa.w);
            float w4 = EDEC_W(pb.x), w5 = EDEC_W(pb.y), w6 = EDEC_W(pb.z), w7 = EDEC_W(pb.w);
            accx = fmaf(w0, f0.x, accx); accy = fmaf(w0, f0.y, accy);
            accx = fmaf(w1, f1.x, accx); accy = fmaf(w1, f1.y, accy);
            accx = fmaf(w2, f2.x, accx); accy = fmaf(w2, f2.y, accy);
            accx = fmaf(w3, f3.x, accx); accy = fmaf(w3, f3.y, accy);
            accx = fmaf(w4, f4.x, accx); accy = fmaf(w4, f4.y, accy);
            accx = fmaf(w5, f5.x, accx); accy = fmaf(w5, f5.y, accy);
            accx = fmaf(w6, f6.x, accx); accy = fmaf(w6, f6.y, accy);
            accx = fmaf(w7, f7.x, accx); accy = fmaf(w7, f7.y, accy);
        }
        if (e + 4 <= e1) {
            uint4 pa = *(const uint4*)(ewp + e);
            __half2 r0 = h2[(size_t)EDEC_S(pa.x) * 64 + l];
            __half2 r1 = h2[(size_t)EDEC_S(pa.y) * 64 + l];
            __half2 r2 = h2[(size_t)EDEC_S(pa.z) * 64 + l];
            __half2 r3 = h2[(size_t)EDEC_S(pa.w) * 64 + l];
            float2 f0 = __half22float2(r0), f1 = __half22float2(r1);
            float2 f2 = __half22float2(r2), f3 = __half22float2(r3);
            float w0 = EDEC_W(pa.x), w1 = EDEC_W(pa.y), w2 = EDEC_W(pa.z), w3 = EDEC_W(pa.w);
            accx = fmaf(w0, f0.x, accx); accy = fmaf(w0, f0.y, accy);
            accx = fmaf(w1, f1.x, accx); accy = fmaf(w1, f1.y, accy);
            accx = fmaf(w2, f2.x, accx); accy = fmaf(w2, f2.y, accy);
            accx = fmaf(w3, f3.x, accx); accy = fmaf(w3, f3.y, accy);
            e += 4;
        }
        while (e < e1) {
            unsigned v = ewp[e];
            float wk = EDEC_W(v);
            float2 f = __half22float2(h2[(size_t)EDEC_S(v) * 64 + l]);
            accx = fmaf(wk, f.x, accx); accy = fmaf(wk, f.y, accy);
            ++e;
        }
        *(__half2*)&As[i][2 * l] = __floats2half2_rn(accx, accy);
    }
}

// Layer 1 fused: hb = tanh(spmm(xh) @ W0). Wave = 16 nodes; no barriers (wave-private LDS).
__global__ __launch_bounds__(256) void fused_l1(const __half* __restrict__ h,
                                                const unsigned* __restrict__ ewp,
                                                const int* __restrict__ rp,
                                                const __half* __restrict__ Wt,
                                                __half* __restrict__ out) {
    __shared__ _Float16 As[4][16][136];
    int wave = threadIdx.x >> 6, l = threadIdx.x & 63;
    int n0 = blockIdx.x * 64 + wave * 16;
    spmm_tile((const __half2*)h, ewp, rp, n0, l, As[wave]);
    int lr = l & 15, lg = l >> 4;
    f16x8 a[4];
#pragma unroll
    for (int kb = 0; kb < 4; ++kb)
        a[kb] = *(const f16x8*)&As[wave][lr][kb * 32 + lg * 8];
    const _Float16* Wf = (const _Float16*)Wt;
#pragma unroll
    for (int ct = 0; ct < 8; ++ct) {
        f32x4 acc = {0.f, 0.f, 0.f, 0.f};
#pragma unroll
        for (int kb = 0; kb < 4; ++kb) {
            f16x8 b = *(const f16x8*)(Wf + (size_t)(ct * 16 + lr) * HH + kb * 32 + lg * 8);
            acc = __builtin_amdgcn_mfma_f32_16x16x32_f16(a[kb], b, acc, 0, 0, 0);
        }
#pragma unroll
        for (int r = 0; r < 4; ++r)
            As[wave][lg * 4 + r][ct * 16 + lr] = (_Float16)fast_tanh(acc[r]);
    }
#pragma unroll
    for (int i = 0; i < 4; ++i) {
        int row = lg + 4 * i;
        f16x8 v = *(const f16x8*)&As[wave][row][lr * 8];
        *(f16x8*)((_Float16*)out + (size_t)(n0 + row) * HH + lr * 8) = v;
    }
}

// Layer 2 + projection fused: g = tanh(spmm(hb) @ W1) @ W2 -> [NPAD][64].
__global__ __launch_bounds__(256) void fused_l2(const __half* __restrict__ h,
                                                const unsigned* __restrict__ ewp,
                                                const int* __restrict__ rp,
                                                const __half* __restrict__ W1t,
                                                const __half* __restrict__ W2t,
                                                __half* __restrict__ gout) {
    __shared__ _Float16 As[4][16][136];
    int wave = threadIdx.x >> 6, l = threadIdx.x & 63;
    int n0 = blockIdx.x * 64 + wave * 16;
    spmm_tile((const __half2*)h, ewp, rp, n0, l, As[wave]);
    int lr = l & 15, lg = l >> 4;
    const _Float16* W1f = (const _Float16*)W1t;
    const _Float16* W2f = (const _Float16*)W2t;
    f16x8 a[4];
#pragma unroll
    for (int kb = 0; kb < 4; ++kb)
        a[kb] = *(const f16x8*)&As[wave][lr][kb * 32 + lg * 8];
#pragma unroll
    for (int ct = 0; ct < 8; ++ct) {
        f32x4 acc = {0.f, 0.f, 0.f, 0.f};
#pragma unroll
        for (int kb = 0; kb < 4; ++kb) {
            f16x8 b = *(const f16x8*)(W1f + (size_t)(ct * 16 + lr) * HH + kb * 32 + lg * 8);
            acc = __builtin_amdgcn_mfma_f32_16x16x32_f16(a[kb], b, acc, 0, 0, 0);
        }
#pragma unroll
        for (int r = 0; r < 4; ++r)
            As[wave][lg * 4 + r][ct * 16 + lr] = (_Float16)fast_tanh(acc[r]);
    }
    f16x8 a2[4];
#pragma unroll
    for (int kb = 0; kb < 4; ++kb)
        a2[kb] = *(const f16x8*)&As[wave][lr][kb * 32 + lg * 8];
#pragma unroll
    for (int ct = 0; ct < 4; ++ct) {
        f32x4 acc = {0.f, 0.f, 0.f, 0.f};
#pragma unroll
        for (int kb = 0; kb < 4; ++kb) {
            f16x8 b = *(const f16x8*)(W2f + (size_t)(ct * 16 + lr) * HH + kb * 32 + lg * 8);
            acc = __builtin_amdgcn_mfma_f32_16x16x32_f16(a2[kb], b, acc, 0, 0, 0);
        }
#pragma unroll
        for (int r = 0; r < 4; ++r)
            As[wave][lg * 4 + r][ct * 16 + lr] = (_Float16)acc[r];
    }
#pragma unroll
    for (int i = 0; i < 2; ++i) {
        int row = (l >> 3) + 8 * i;
        f16x8 v = *(const f16x8*)&As[wave][row][(l & 7) * 8];
        *(f16x8*)((_Float16*)gout + (size_t)(n0 + row) * 64 + (l & 7) * 8) = v;
    }
}

// Layer 3: out = tanh(spmm(g)); g rows padded to 64 halves (128B). 8 lanes/row.
__global__ __launch_bounds__(256) void spmm40_tanh(const __half* __restrict__ gpad,
                                                   const unsigned* __restrict__ ewp,
                                                   const int* __restrict__ rp,
                                                   float* __restrict__ out) {
    int node = blockIdx.x * 4 + (threadIdx.x >> 6);
    int l = threadIdx.x & 63;
    if (node >= NN) return;
    int e0 = __builtin_amdgcn_readfirstlane(rp[node]);
    int e1 = __builtin_amdgcn_readfirstlane(rp[node + 1]);
    int g = l >> 3, r = l & 7;
    const f16x8* __restrict__ grw = (const f16x8*)gpad;
    float acc[8] = {};
    int e = e0;
    while ((e & 1) && e < e1) {           // peel to 8B alignment
        unsigned v = ewp[e];
        float wk = (g == 0) ? EDEC_W(v) : 0.f;
        f16x8 vv = grw[(size_t)EDEC_S(v) * 8 + r];
#pragma unroll
        for (int j = 0; j < 8; ++j) acc[j] = fmaf(wk, (float)vv[j], acc[j]);
        ++e;
    }
    int e16 = e + ((e1 - e) & ~15);
    for (; e < e16; e += 16) {            // group g owns edges e+2g, e+2g+1
        uint2 pa = *(const uint2*)(ewp + e + 2 * g);
        f16x8 v0 = grw[(size_t)EDEC_S(pa.x) * 8 + r];
        f16x8 v1 = grw[(size_t)EDEC_S(pa.y) * 8 + r];
        float w0 = EDEC_W(pa.x), w1 = EDEC_W(pa.y);
#pragma unroll
        for (int j = 0; j < 8; ++j) acc[j] = fmaf(w0, (float)v0[j], acc[j]);
#pragma unroll
        for (int j = 0; j < 8; ++j) acc[j] = fmaf(w1, (float)v1[j], acc[j]);
    }
    if (e < e1) {                         // masked tail (<16 edges)
#pragma unroll
        for (int k = 0; k < 2; ++k) {
            int idx = e + 2 * g + k;
            bool val = idx < e1;
            unsigned v = ewp[val ? idx : e0];
            float wk = val ? EDEC_W(v) : 0.f;
            f16x8 vv = grw[(size_t)EDEC_S(v) * 8 + r];
#pragma unroll
            for (int j = 0; j < 8; ++j) acc[j] = fmaf(wk, (float)vv[j], acc[j]);
        }
    }
#pragma unroll
    for (int j = 0; j < 8; ++j) {
        acc[j] += __shfl_xor(acc[j], 8);
        acc[j] += __shfl_xor(acc[j], 16);
        acc[j] += __shfl_xor(acc[j], 32);
    }
    if (l < 5) {
        float o[8];
#pragma unroll
        for (int j = 0; j < 8; ++j) o[j] = fast_tanh(acc[j]);
        *(float4*)(out + (size_t)node * CC + r * 8) = *(float4*)&o[0];
        *(float4*)(out + (size_t)node * CC + r * 8 + 4) = *(float4*)&o[4];
    }
}

extern "C" void kernel_launch(void* const* d_in, const int* in_sizes, int n_in,
                              void* d_out, int out_size, void* d_ws, size_t ws_size,
                              hipStream_t stream) {
    const float* x    = (const float*)d_in[0];
    const int*   esrc = (const int*)d_in[1];
    const int*   edst = (const int*)d_in[2];
    const float* ew_f = (const float*)d_in[3];
    const float* W0   = (const float*)d_in[4];
    const float* W1   = (const float*)d_in[5];
    const float* W2   = (const float*)d_in[6];
    float* out = (float*)d_out;

    char* ws = (char*)d_ws;
    size_t off = 0;
    int* rp = (int*)(ws + off);          off += (((size_t)(NN + 1) * 4) + 511) & ~(size_t)511;
    __half* buf0 = (__half*)(ws + off);  off += (size_t)NPAD * HH * sizeof(__half); // xh, later g
    __half* hb = (__half*)(ws + off);    off += (size_t)NPAD * HH * sizeof(__half);
    unsigned* ewp = (unsigned*)(ws + off); off += (size_t)EE * sizeof(unsigned);
    __half* W0t = (__half*)(ws + off);   off += (size_t)HH * HH * sizeof(__half);
    __half* W1t = (__half*)(ws + off);   off += (size_t)HH * HH * sizeof(__half);
    __half* W2t = (__half*)(ws + off);   off += (size_t)64 * HH * sizeof(__half);
    __half* xh = buf0;
    __half* gb = buf0;  // alias: xh dead after fused_l1

    build_rp<<<(NN + 256) / 256, 256, 0, stream>>>(edst, rp);
    prep_all<<<9440, 256, 0, stream>>>(x, esrc, ew_f, W0, W1, W2,
                                       xh, ewp, W0t, W1t, W2t);

    int grid = NPAD / 64;
    fused_l1<<<grid, 256, 0, stream>>>(xh, ewp, rp, W0t, hb);
    fused_l2<<<grid, 256, 0, stream>>>(hb, ewp, rp, W1t, W2t, gb);
    spmm40_tanh<<<NN / 4, 256, 0, stream>>>(gb, ewp, rp, out);
}

// Round 8
// 504.663 us; speedup vs baseline: 1.0059x; 1.0059x over previous
//
#include <hip/hip_runtime.h>
#include <hip/hip_fp16.h>

#define NN 100000
#define NPAD 100096   // 64*1564
#define EE 3200000
#define HH 128
#define CC 40
#define NT 16         // src tiles of 8192 rows (2MB of h) for L2 locality

typedef _Float16 f16x8 __attribute__((ext_vector_type(8)));
typedef float f32x4 __attribute__((ext_vector_type(4)));

#define EDEC_W(v) ((float)((v) >> 17) * (1.f / 32767.f))
#define EDEC_S(v) ((v) & 131071u)

// tanh(x) = (e^2x - 1)/(e^2x + 1); clamp avoids inf*0=NaN. ~6 VALU ops.
__device__ __forceinline__ float fast_tanh(float x) {
    float t = __expf(2.f * fminf(x, 15.f));
    return (t - 1.f) * __builtin_amdgcn_rcpf(t + 1.f);
}

// rp[i] = lower_bound(edge_dst, i) — edge_dst is sorted.
__global__ void build_rp(const int* __restrict__ dst, int* __restrict__ rp) {
    int i = blockIdx.x * blockDim.x + threadIdx.x;
    if (i > NN) return;
    int lo = 0, hi = EE;
    while (lo < hi) {
        int mid = (lo + hi) >> 1;
        if (dst[mid] < i) lo = mid + 1; else hi = mid;
    }
    rp[i] = lo;
}

// prep: x->fp16; edges packed to 4B (src 17b | w 15b fixed); weights fp16^T.
__global__ __launch_bounds__(256) void prep_all(const float* __restrict__ x,
                                                const int* __restrict__ src,
                                                const float* __restrict__ w,
                                                const float* __restrict__ W0,
                                                const float* __restrict__ W1,
                                                const float* __restrict__ W2,
                                                __half* __restrict__ xh,
                                                unsigned* __restrict__ ewp,
                                                __half* __restrict__ W0t,
                                                __half* __restrict__ W1t,
                                                __half* __restrict__ W2t) {
    int b = blockIdx.x, tid = threadIdx.x;
    if (b < 6250) {                       // x: 12.8M elems, 8/thread
        int base = (b * 256 + tid) * 8;
        float4 a = *(const float4*)(x + base);
        float4 c = *(const float4*)(x + base + 4);
        __half2 h[4];
        h[0] = __floats2half2_rn(a.x, a.y);
        h[1] = __floats2half2_rn(a.z, a.w);
        h[2] = __floats2half2_rn(c.x, c.y);
        h[3] = __floats2half2_rn(c.z, c.w);
        *(float4*)(xh + base) = *(float4*)h;
    } else if (b < 9375) {                // pack 4 edges/thread
        int i = (b - 6250) * 256 + tid;   // < 800000
        int4 s = ((const int4*)src)[i];
        float4 f = ((const float4*)w)[i];
        uint4 p;
        p.x = (unsigned)s.x | ((unsigned)(f.x * 32767.f + 0.5f) << 17);
        p.y = (unsigned)s.y | ((unsigned)(f.y * 32767.f + 0.5f) << 17);
        p.z = (unsigned)s.z | ((unsigned)(f.z * 32767.f + 0.5f) << 17);
        p.w = (unsigned)s.w | ((unsigned)(f.w * 32767.f + 0.5f) << 17);
        ((uint4*)ewp)[i] = p;
    } else {                              // W0t,W1t [128][128]; W2t [64][128]
        int i = (b - 9375) * 256 + tid;
        if (i < HH * HH) {
            int c = i >> 7, k = i & 127;
            W0t[i] = __float2half_rn(W0[k * HH + c]);
            W1t[i] = __float2half_rn(W1[k * HH + c]);
        }
        if (i < 64 * HH) {
            int c = i >> 7, k = i & 127;
            W2t[i] = __float2half_rn(c < CC ? W2[k * CC + c] : 0.f);
        }
    }
}

// Per-node stable bucket sort of edges by src-tile (src>>13, 16 buckets).
// One wave per node; ballot-based count + ranked scatter. Segment-sum is
// order-independent, so this is legal; it creates temporal L2 locality.
__global__ __launch_bounds__(256) void sort_edges(const unsigned* __restrict__ in,
                                                  const int* __restrict__ rp,
                                                  unsigned* __restrict__ outp) {
    int node = blockIdx.x * 4 + (threadIdx.x >> 6);
    int l = threadIdx.x & 63;
    if (node >= NN) return;
    int e0 = __builtin_amdgcn_readfirstlane(rp[node]);
    int e1 = __builtin_amdgcn_readfirstlane(rp[node + 1]);
    int count[NT];
#pragma unroll
    for (int t = 0; t < NT; ++t) count[t] = 0;
    for (int e = e0; e < e1; e += 64) {   // pass 1: histogram
        int idx = e + l;
        bool val = idx < e1;
        unsigned v = val ? in[idx] : 0u;
        int t = val ? (int)(EDEC_S(v) >> 13) : -1;
#pragma unroll
        for (int tt = 0; tt < NT; ++tt)
            count[tt] += __popcll(__ballot(t == tt));
    }
    int base[NT];
    int run = e0;
#pragma unroll
    for (int tt = 0; tt < NT; ++tt) { base[tt] = run; run += count[tt]; }
    unsigned long long lmask = (1ull << l) - 1ull;
    for (int e = e0; e < e1; e += 64) {   // pass 2: ranked scatter (stable)
        int idx = e + l;
        bool val = idx < e1;
        unsigned v = val ? in[idx] : 0u;
        int t = val ? (int)(EDEC_S(v) >> 13) : -1;
#pragma unroll
        for (int tt = 0; tt < NT; ++tt) {
            unsigned long long b = __ballot(t == tt);
            if (t == tt) outp[base[tt] + __popcll(b & lmask)] = v;
            base[tt] += __popcll(b);
        }
    }
}

// One wave per node, 4 nodes/block. 16 lanes x 16B cover a 256B row;
// 4 lane-groups = 4 edges per gather instr; uint4 meta = 4 edges/group.
__global__ __launch_bounds__(256) void spmm_h16(const __half* __restrict__ h,
                                                const unsigned* __restrict__ ewp,
                                                const int* __restrict__ rp,
                                                __half* __restrict__ out) {
    int node = blockIdx.x * 4 + (threadIdx.x >> 6);
    int l = threadIdx.x & 63;
    if (node >= NN) return;
    int e0 = __builtin_amdgcn_readfirstlane(rp[node]);
    int e1 = __builtin_amdgcn_readfirstlane(rp[node + 1]);
    int g = l >> 4, r = l & 15;
    const f16x8* __restrict__ hrow = (const f16x8*)h;
    float acc[8] = {};
    int e = e0;
    while ((e & 3) && e < e1) {           // peel to 16B alignment of ewp+e
        unsigned v = ewp[e];
        float wk = (g == 0) ? EDEC_W(v) : 0.f;   // all groups load same row; only g0 counts
        f16x8 vv = hrow[(size_t)EDEC_S(v) * 16 + r];
#pragma unroll
        for (int j = 0; j < 8; ++j) acc[j] = fmaf(wk, (float)vv[j], acc[j]);
        ++e;
    }
    int e16 = e + ((e1 - e) & ~15);
    for (; e < e16; e += 16) {            // group g owns edges e+4g .. e+4g+3
        uint4 p = *(const uint4*)(ewp + e + 4 * g);
        f16x8 v0 = hrow[(size_t)EDEC_S(p.x) * 16 + r];
        f16x8 v1 = hrow[(size_t)EDEC_S(p.y) * 16 + r];
        f16x8 v2 = hrow[(size_t)EDEC_S(p.z) * 16 + r];
        f16x8 v3 = hrow[(size_t)EDEC_S(p.w) * 16 + r];
        float w0 = EDEC_W(p.x), w1 = EDEC_W(p.y), w2 = EDEC_W(p.z), w3 = EDEC_W(p.w);
#pragma unroll
        for (int j = 0; j < 8; ++j) acc[j] = fmaf(w0, (float)v0[j], acc[j]);
#pragma unroll
        for (int j = 0; j < 8; ++j) acc[j] = fmaf(w1, (float)v1[j], acc[j]);
#pragma unroll
        for (int j = 0; j < 8; ++j) acc[j] = fmaf(w2, (float)v2[j], acc[j]);
#pragma unroll
        for (int j = 0; j < 8; ++j) acc[j] = fmaf(w3, (float)v3[j], acc[j]);
    }
    if (e < e1) {                         // masked tail (<16 edges)
#pragma unroll
        for (int k = 0; k < 4; ++k) {
            int idx = e + 4 * g + k;
            bool val = idx < e1;
            unsigned v = ewp[val ? idx : e0];
            float wk = val ? EDEC_W(v) : 0.f;
            f16x8 vv = hrow[(size_t)EDEC_S(v) * 16 + r];
#pragma unroll
            for (int j = 0; j < 8; ++j) acc[j] = fmaf(wk, (float)vv[j], acc[j]);
        }
    }
#pragma unroll
    for (int j = 0; j < 8; ++j) {
        acc[j] += __shfl_xor(acc[j], 16);
        acc[j] += __shfl_xor(acc[j], 32);
    }
    if (l < 16) {
        __half2 hv[4];
#pragma unroll
        for (int j = 0; j < 4; ++j) hv[j] = __floats2half2_rn(acc[2 * j], acc[2 * j + 1]);
        *(float4*)(out + (size_t)node * HH + r * 8) = *(float4*)hv;
    }
}

// Layer 3: out = tanh(spmm(g)); g rows padded to 64 halves (128B). 8 lanes/row.
__global__ __launch_bounds__(256) void spmm40_tanh(const __half* __restrict__ gpad,
                                                   const unsigned* __restrict__ ewp,
                                                   const int* __restrict__ rp,
                                                   float* __restrict__ out) {
    int node = blockIdx.x * 4 + (threadIdx.x >> 6);
    int l = threadIdx.x & 63;
    if (node >= NN) return;
    int e0 = __builtin_amdgcn_readfirstlane(rp[node]);
    int e1 = __builtin_amdgcn_readfirstlane(rp[node + 1]);
    int g = l >> 3, r = l & 7;
    const f16x8* __restrict__ grw = (const f16x8*)gpad;
    float acc[8] = {};
    int e = e0;
    while ((e & 1) && e < e1) {           // peel to 8B alignment
        unsigned v = ewp[e];
        float wk = (g == 0) ? EDEC_W(v) : 0.f;
        f16x8 vv = grw[(size_t)EDEC_S(v) * 8 + r];
#pragma unroll
        for (int j = 0; j < 8; ++j) acc[j] = fmaf(wk, (float)vv[j], acc[j]);
        ++e;
    }
    int e16 = e + ((e1 - e) & ~15);
    for (; e < e16; e += 16) {            // group g owns edges e+2g, e+2g+1
        uint2 pa = *(const uint2*)(ewp + e + 2 * g);
        f16x8 v0 = grw[(size_t)EDEC_S(pa.x) * 8 + r];
        f16x8 v1 = grw[(size_t)EDEC_S(pa.y) * 8 + r];
        float w0 = EDEC_W(pa.x), w1 = EDEC_W(pa.y);
#pragma unroll
        for (int j = 0; j < 8; ++j) acc[j] = fmaf(w0, (float)v0[j], acc[j]);
#pragma unroll
        for (int j = 0; j < 8; ++j) acc[j] = fmaf(w1, (float)v1[j], acc[j]);
    }
    if (e < e1) {                         // masked tail (<16 edges)
#pragma unroll
        for (int k = 0; k < 2; ++k) {
            int idx = e + 2 * g + k;
            bool val = idx < e1;
            unsigned v = ewp[val ? idx : e0];
            float wk = val ? EDEC_W(v) : 0.f;
            f16x8 vv = grw[(size_t)EDEC_S(v) * 8 + r];
#pragma unroll
            for (int j = 0; j < 8; ++j) acc[j] = fmaf(wk, (float)vv[j], acc[j]);
        }
    }
#pragma unroll
    for (int j = 0; j < 8; ++j) {
        acc[j] += __shfl_xor(acc[j], 8);
        acc[j] += __shfl_xor(acc[j], 16);
        acc[j] += __shfl_xor(acc[j], 32);
    }
    if (l < 5) {
        float o[8];
#pragma unroll
        for (int j = 0; j < 8; ++j) o[j] = fast_tanh(acc[j]);
        *(float4*)(out + (size_t)node * CC + r * 8) = *(float4*)&o[0];
        *(float4*)(out + (size_t)node * CC + r * 8 + 4) = *(float4*)&o[4];
    }
}

// Layer-1 GEMM: out = tanh(A @ W) fp16, epilogue coalesced via LDS.
__global__ __launch_bounds__(256) void gemm_tanh_mfma(const __half* __restrict__ A,
                                                      const __half* __restrict__ Wt,
                                                      __half* __restrict__ out) {
    __shared__ _Float16 st[4][16][136];
    int wave = threadIdx.x >> 6, l = threadIdx.x & 63;
    int r0 = blockIdx.x * 64 + wave * 16;
    int lr = l & 15, lg = l >> 4;
    const _Float16* Af = (const _Float16*)A;
    const _Float16* Wf = (const _Float16*)Wt;
    f16x8 a[4];
#pragma unroll
    for (int kb = 0; kb < 4; ++kb)
        a[kb] = *(const f16x8*)(Af + (size_t)(r0 + lr) * HH + kb * 32 + lg * 8);
#pragma unroll
    for (int ct = 0; ct < 8; ++ct) {
        f32x4 acc = {0.f, 0.f, 0.f, 0.f};
#pragma unroll
        for (int kb = 0; kb < 4; ++kb) {
            f16x8 b = *(const f16x8*)(Wf + (size_t)(ct * 16 + lr) * HH + kb * 32 + lg * 8);
            acc = __builtin_amdgcn_mfma_f32_16x16x32_f16(a[kb], b, acc, 0, 0, 0);
        }
#pragma unroll
        for (int r = 0; r < 4; ++r)
            st[wave][lg * 4 + r][ct * 16 + lr] = (_Float16)fast_tanh(acc[r]);
    }
#pragma unroll
    for (int i = 0; i < 4; ++i) {
        int row = lg + 4 * i;
        int grow = r0 + row;
        f16x8 v = *(const f16x8*)&st[wave][row][lr * 8];
        if (grow < NN)
            *(f16x8*)((_Float16*)out + (size_t)grow * HH + lr * 8) = v;
    }
}

// Layer-2 fused: h2 = tanh(A @ W1) (LDS only), g = h2 @ W2 -> gout [NPAD][64] fp16.
__global__ __launch_bounds__(256) void gemm2_fused(const __half* __restrict__ A,
                                                   const __half* __restrict__ W1t,
                                                   const __half* __restrict__ W2t,
                                                   __half* __restrict__ gout) {
    __shared__ _Float16 st[4][16][136];
    int wave = threadIdx.x >> 6, l = threadIdx.x & 63;
    int r0 = blockIdx.x * 64 + wave * 16;
    int lr = l & 15, lg = l >> 4;
    const _Float16* Af = (const _Float16*)A;
    const _Float16* W1f = (const _Float16*)W1t;
    const _Float16* W2f = (const _Float16*)W2t;
    f16x8 a[4];
#pragma unroll
    for (int kb = 0; kb < 4; ++kb)
        a[kb] = *(const f16x8*)(Af + (size_t)(r0 + lr) * HH + kb * 32 + lg * 8);
#pragma unroll
    for (int ct = 0; ct < 8; ++ct) {
        f32x4 acc = {0.f, 0.f, 0.f, 0.f};
#pragma unroll
        for (int kb = 0; kb < 4; ++kb) {
            f16x8 b = *(const f16x8*)(W1f + (size_t)(ct * 16 + lr) * HH + kb * 32 + lg * 8);
            acc = __builtin_amdgcn_mfma_f32_16x16x32_f16(a[kb], b, acc, 0, 0, 0);
        }
#pragma unroll
        for (int r = 0; r < 4; ++r)
            st[wave][lg * 4 + r][ct * 16 + lr] = (_Float16)fast_tanh(acc[r]);
    }
    f16x8 a2[4];
#pragma unroll
    for (int kb = 0; kb < 4; ++kb)
        a2[kb] = *(const f16x8*)&st[wave][lr][kb * 32 + lg * 8];
#pragma unroll
    for (int ct = 0; ct < 4; ++ct) {
        f32x4 acc = {0.f, 0.f, 0.f, 0.f};
#pragma unroll
        for (int kb = 0; kb < 4; ++kb) {
            f16x8 b = *(const f16x8*)(W2f + (size_t)(ct * 16 + lr) * HH + kb * 32 + lg * 8);
            acc = __builtin_amdgcn_mfma_f32_16x16x32_f16(a2[kb], b, acc, 0, 0, 0);
        }
#pragma unroll
        for (int r = 0; r < 4; ++r)
            st[wave][lg * 4 + r][ct * 16 + lr] = (_Float16)acc[r];
    }
#pragma unroll
    for (int i = 0; i < 2; ++i) {
        int row = (l >> 3) + 8 * i;
        int grow = r0 + row;
        f16x8 v = *(const f16x8*)&st[wave][row][(l & 7) * 8];
        if (grow < NN)
            *(f16x8*)((_Float16*)gout + (size_t)grow * 64 + (l & 7) * 8) = v;
    }
}

extern "C" void kernel_launch(void* const* d_in, const int* in_sizes, int n_in,
                              void* d_out, int out_size, void* d_ws, size_t ws_size,
                              hipStream_t stream) {
    const float* x    = (const float*)d_in[0];
    const int*   esrc = (const int*)d_in[1];
    const int*   edst = (const int*)d_in[2];
    const float* ew_f = (const float*)d_in[3];
    const float* W0   = (const float*)d_in[4];
    const float* W1   = (const float*)d_in[5];
    const float* W2   = (const float*)d_in[6];
    float* out = (float*)d_out;

    char* ws = (char*)d_ws;
    size_t off = 0;
    int* rp = (int*)(ws + off);            off += (((size_t)(NN + 1) * 4) + 511) & ~(size_t)511;
    __half* buf0 = (__half*)(ws + off);    off += (size_t)NPAD * HH * sizeof(__half); // xh, later g
    __half* sA = (__half*)(ws + off);      off += (size_t)NPAD * HH * sizeof(__half);
    __half* hb = (__half*)(ws + off);      off += (size_t)NPAD * HH * sizeof(__half);
    unsigned* ewp = (unsigned*)(ws + off); off += (size_t)EE * sizeof(unsigned);
    unsigned* ews = (unsigned*)(ws + off); off += (size_t)EE * sizeof(unsigned); // tile-sorted
    __half* W0t = (__half*)(ws + off);     off += (size_t)HH * HH * sizeof(__half);
    __half* W1t = (__half*)(ws + off);     off += (size_t)HH * HH * sizeof(__half);
    __half* W2t = (__half*)(ws + off);     off += (size_t)64 * HH * sizeof(__half);
    __half* xh = buf0;
    __half* gb = buf0;  // alias: xh dead after first spmm

    build_rp<<<(NN + 256) / 256, 256, 0, stream>>>(edst, rp);
    prep_all<<<9440, 256, 0, stream>>>(x, esrc, ew_f, W0, W1, W2,
                                       xh, ewp, W0t, W1t, W2t);
    sort_edges<<<NN / 4, 256, 0, stream>>>(ewp, rp, ews);

    int gemm_grid = NPAD / 64;
    // layer 1
    spmm_h16<<<NN / 4, 256, 0, stream>>>(xh, ews, rp, sA);
    gemm_tanh_mfma<<<gemm_grid, 256, 0, stream>>>(sA, W0t, hb);
    // layer 2 + output projection fused (h2 never hits global)
    spmm_h16<<<NN / 4, 256, 0, stream>>>(hb, ews, rp, sA);
    gemm2_fused<<<gemm_grid, 256, 0, stream>>>(sA, W1t, W2t, gb);
    // layer 3: out = tanh(spmm(g))
    spmm40_tanh<<<NN / 4, 256, 0, stream>>>(gb, ews, rp, out);
}